// Round 1
// baseline (407.294 us; speedup 1.0000x reference)
//
#include <hip/hip_runtime.h>

#define NNODES 25000
#define NEDGES 400000
#define HDIM   32
#define NHEADS 10
#define NCOLS  320          // HEADS*HDIM
#define KDIM   64           // 2*HDIM
#define NEG    0.2f
#define EPSV   1e-5f
#define NQ     40000        // NEDGES/10 edge-groups
#define GRID_MAIN  5000
#define ITERS_MAIN 8        // GRID_MAIN*ITERS_MAIN == NQ

typedef __bf16 bf16x8 __attribute__((ext_vector_type(8)));
typedef float  f32x4  __attribute__((ext_vector_type(4)));

__device__ __forceinline__ float leaky_f(float v) { return v >= 0.0f ? v : NEG * v; }

__global__ void agat_init_out(float* __restrict__ out, const float* __restrict__ bias) {
  int i = blockIdx.x * 256 + threadIdx.x;
  if (i < NNODES * HDIM) out[i] = bias[i & (HDIM - 1)];
}

// Block = 320 threads = 5 waves. Wave w owns heads {2w,2w+1} = columns [64w,64w+64).
// One iteration processes edge-group q: edges 10q..10q+9 as rows 0..9 of a 16-row
// M-tile (rows 10..15 zero-padded). mfma_f32_16x16x32_bf16, K=64 -> 2 k-steps,
// 4 N-tiles per wave, for both x_i (att only) and x_j (att + messages).
__global__ __launch_bounds__(320) void agat_fused(
    const float* __restrict__ x,
    const int*   __restrict__ eidx,
    const float* __restrict__ ea,
    const float* __restrict__ W,
    const float* __restrict__ att,
    const float* __restrict__ gamma,
    const float* __restrict__ beta,
    const float* __restrict__ rmean,
    const float* __restrict__ rvar,
    float*       __restrict__ out)
{
  const int tid = threadIdx.x;
  const int w  = tid >> 6;   // wave 0..4
  const int l  = tid & 63;
  const int lq = l >> 4;     // lane quarter
  const int lr = l & 15;

  __shared__ __align__(16) __bf16 xci_l[16 * KDIM];  // [row][k], XOR-swizzled rows
  __shared__ __align__(16) __bf16 xcj_l[16 * KDIM];
  __shared__ float sm[NHEADS * 16];                  // logits -> softmax weights

  // zero the 6 pad rows once (never overwritten; swizzle is a within-row permutation)
  for (int idx = 10 * KDIM + tid; idx < 16 * KDIM; idx += 320) {
    xci_l[idx] = (__bf16)0.0f;
    xcj_l[idx] = (__bf16)0.0f;
  }

  // ---- B-operand fragments of W (loaded once): lane l -> col 64w+16t+lr, k = 32ks+8*lq+j
  bf16x8 wf[4][2];
#pragma unroll
  for (int t = 0; t < 4; ++t)
#pragma unroll
    for (int ks = 0; ks < 2; ++ks)
#pragma unroll
      for (int j = 0; j < 8; ++j) {
        int k = 32 * ks + lq * 8 + j;
        int c = 64 * w + 16 * t + lr;
        wf[t][ks][j] = (__bf16)W[k * NCOLS + c];
      }

  // att values for this lane's columns: head h = 2w+(t>>1), in-head col cc = 16*(t&1)+lr
  float atti[4], attj[4];
#pragma unroll
  for (int t = 0; t < 4; ++t) {
    int h  = 2 * w + (t >> 1);
    int cc = 16 * (t & 1) + lr;
    atti[t] = att[h * 64 + cc];
    attj[t] = att[h * 64 + 32 + cc];
  }

  // GroupNorm (eval): alpha_hat = leaky(logit)*gs + gb  per head
  float gs[2], gb[2];
#pragma unroll
  for (int hh = 0; hh < 2; ++hh) {
    int h = 2 * w + hh;
    float inv = rsqrtf(rvar[h] + EPSV);
    gs[hh] = inv * gamma[h];
    gb[hh] = beta[h] - rmean[h] * inv * gamma[h];
  }

  const int eL = tid >> 5;   // staging: edge row 0..9
  const int dd = tid & 31;   // staging: feature dim 0..31

  for (int it = 0; it < ITERS_MAIN; ++it) {
    const int q = blockIdx.x + it * GRID_MAIN;   // < NQ by construction

    // ---------- stage 10 edges into rows 0..9 (bf16, XOR-swizzled) ----------
    {
      const int e  = q * 10 + eL;
      const int ri = eidx[e];            // row (i side, also segment id)
      const int ci = eidx[NEDGES + e];   // col (j side)
      const float xiv = x[ri * HDIM + dd];
      const float xjv = x[ci * HDIM + dd];
      const float eav = ea[e * HDIM + dd];
      const int swz = (eL & 7) << 4;
      char* pi = (char*)xci_l;
      char* pj = (char*)xcj_l;
      const int o1 = (eL * 128 + dd * 2) ^ swz;        // k = dd
      const int o2 = (eL * 128 + 64 + dd * 2) ^ swz;   // k = 32+dd (edge_attr)
      *(__bf16*)(pi + o1) = (__bf16)xiv;
      *(__bf16*)(pi + o2) = (__bf16)eav;
      *(__bf16*)(pj + o1) = (__bf16)xjv;
      *(__bf16*)(pj + o2) = (__bf16)eav;
    }
    __syncthreads();

    // ---------- MFMA: lin_i / lin_j for this wave's 64 columns ----------
    f32x4 acc_i[4], acc_j[4];
#pragma unroll
    for (int t = 0; t < 4; ++t) {
      acc_i[t] = (f32x4){0.f, 0.f, 0.f, 0.f};
      acc_j[t] = (f32x4){0.f, 0.f, 0.f, 0.f};
    }
#pragma unroll
    for (int ks = 0; ks < 2; ++ks) {
      const int off = (lr * 128 + ks * 64 + lq * 16) ^ ((lr & 7) << 4);
      bf16x8 ai = *(const bf16x8*)((const char*)xci_l + off);
      bf16x8 aj = *(const bf16x8*)((const char*)xcj_l + off);
#pragma unroll
      for (int t = 0; t < 4; ++t) {
        acc_i[t] = __builtin_amdgcn_mfma_f32_16x16x32_bf16(ai, wf[t][ks], acc_i[t], 0, 0, 0);
        acc_j[t] = __builtin_amdgcn_mfma_f32_16x16x32_bf16(aj, wf[t][ks], acc_j[t], 0, 0, 0);
      }
    }

    // D layout: lane holds D[row=lq*4+p][col=16t+lr]  (rows are edges)
    // ---------- leaky + attention-dot partials ----------
    float lj[4][4];
    float plog[2][4];
#pragma unroll
    for (int hh = 0; hh < 2; ++hh)
#pragma unroll
      for (int p = 0; p < 4; ++p) plog[hh][p] = 0.f;
#pragma unroll
    for (int t = 0; t < 4; ++t) {
      const int hh = t >> 1;
#pragma unroll
      for (int p = 0; p < 4; ++p) {
        float xi = leaky_f(acc_i[t][p]);
        float xj = leaky_f(acc_j[t][p]);
        lj[t][p] = xj;
        plog[hh][p] += xi * atti[t] + xj * attj[t];
      }
    }
    // reduce logits over the 16 column lanes (stays within quarter)
#pragma unroll
    for (int m = 1; m <= 8; m <<= 1)
#pragma unroll
      for (int hh = 0; hh < 2; ++hh)
#pragma unroll
        for (int p = 0; p < 4; ++p)
          plog[hh][p] += __shfl_xor(plog[hh][p], m, 64);

    // leaky -> GroupNorm affine, publish per-(head,edge) logits
    if (lr == 0) {
#pragma unroll
      for (int hh = 0; hh < 2; ++hh)
#pragma unroll
        for (int p = 0; p < 4; ++p)
          sm[(2 * w + hh) * 16 + lq * 4 + p] = leaky_f(plog[hh][p]) * gs[hh] + gb[hh];
    }
    __syncthreads();

    // ---------- softmax over 10 heads, one thread per edge row ----------
    if (tid < 16) {
      float v[NHEADS];
      float mx = -1e30f;
#pragma unroll
      for (int h = 0; h < NHEADS; ++h) { v[h] = sm[h * 16 + tid]; mx = fmaxf(mx, v[h]); }
      float s = 0.f;
#pragma unroll
      for (int h = 0; h < NHEADS; ++h) { v[h] = __expf(v[h] - mx); s += v[h]; }
      const float inv = 1.f / s;
#pragma unroll
      for (int h = 0; h < NHEADS; ++h) sm[h * 16 + tid] = v[h] * inv;
    }
    __syncthreads();

    // ---------- messages, 16-row group-sum, scatter ----------
#pragma unroll
    for (int t = 0; t < 4; ++t) {
      const int h = 2 * w + (t >> 1);
      float s_t = 0.f;
#pragma unroll
      for (int p = 0; p < 4; ++p)
        s_t += lj[t][p] * sm[h * 16 + lq * 4 + p];   // pad rows: lj==0
      s_t += __shfl_xor(s_t, 16, 64);
      s_t += __shfl_xor(s_t, 32, 64);
      if (lq == 0) {
        // slot a = h*40000 + q consumes this (group, head); dest node row[a]
        const int a = h * NQ + q;
        const int n = eidx[a];
        atomicAdd(&out[n * HDIM + 16 * (t & 1) + lr], 0.1f * s_t);
      }
    }
    // next iteration's staging is ordered by its own __syncthreads()
  }
}

extern "C" void kernel_launch(void* const* d_in, const int* in_sizes, int n_in,
                              void* d_out, int out_size, void* d_ws, size_t ws_size,
                              hipStream_t stream) {
  const float* x     = (const float*)d_in[0];
  const int*   eidx  = (const int*)  d_in[1];
  const float* ea    = (const float*)d_in[2];
  const float* W     = (const float*)d_in[3];
  const float* att   = (const float*)d_in[4];
  const float* bias  = (const float*)d_in[5];
  const float* gamma = (const float*)d_in[6];
  const float* beta  = (const float*)d_in[7];
  const float* rmean = (const float*)d_in[8];
  const float* rvar  = (const float*)d_in[9];
  float* out = (float*)d_out;

  agat_init_out<<<(NNODES * HDIM + 255) / 256, 256, 0, stream>>>(out, bias);
  agat_fused<<<GRID_MAIN, 320, 0, stream>>>(x, eidx, ea, W, att, gamma, beta,
                                            rmean, rvar, out);
}

// Round 2
// 328.376 us; speedup vs baseline: 1.2403x; 1.2403x over previous
//
#include <hip/hip_runtime.h>

#define NNODES 25000
#define NEDGES 400000
#define HDIM   32
#define NHEADS 10
#define NCOLS  320          // HEADS*HDIM
#define NEG    0.2f
#define EPSV   1e-5f
#define NQ     40000        // NEDGES/10 edge-groups
#define NB     8            // edge-groups (tiles) per block
#define GRID_MAIN (NQ / NB) // 5000 blocks, one shot each

typedef __bf16 bf16x4 __attribute__((ext_vector_type(4)));
typedef __bf16 bf16x8 __attribute__((ext_vector_type(8)));
typedef float  f32x4  __attribute__((ext_vector_type(4)));

__device__ __forceinline__ float leaky_f(float v) { return v >= 0.0f ? v : NEG * v; }

__device__ __forceinline__ bf16x4 cvt4(float4 v) {
  bf16x4 r; r[0] = (__bf16)v.x; r[1] = (__bf16)v.y; r[2] = (__bf16)v.z; r[3] = (__bf16)v.w;
  return r;
}

__global__ void agat_init_out(float* __restrict__ out, const float* __restrict__ bias) {
  int i = blockIdx.x * 256 + threadIdx.x;
  if (i < NNODES * HDIM) out[i] = bias[i & (HDIM - 1)];
}

// Block = 320 threads = 5 waves; wave w owns heads {2w, 2w+1} = cols [64w, 64w+64).
// Block processes NB=8 edge-groups; group nt = 16-row M-tile (10 real edges + 6 zero pads).
// lin = leaky(Xrow@W1 + ea@W2): the ea@W2 term C is shared between x_i and x_j sides,
// so LDS holds three [16][32] bf16 tiles per group (xi, xj, ea) and logits cost 12 MFMAs/tile.
// Pass 2 recomputes the j-side (8 MFMAs/tile) instead of carrying lj across the softmax barrier.
__global__ __launch_bounds__(320) void agat_fused(
    const float* __restrict__ x,
    const int*   __restrict__ eidx,
    const float* __restrict__ ea,
    const float* __restrict__ W,
    const float* __restrict__ att,
    const float* __restrict__ gamma,
    const float* __restrict__ beta,
    const float* __restrict__ rmean,
    const float* __restrict__ rvar,
    float*       __restrict__ out)
{
  const int tid = threadIdx.x;
  const int w  = tid >> 6;   // wave 0..4
  const int l  = tid & 63;
  const int lq = l >> 4;     // lane quarter
  const int lr = l & 15;

  __shared__ __align__(16) __bf16 xi_l[NB * 16 * 32];  // 8 KB, rows XOR-swizzled within 64B
  __shared__ __align__(16) __bf16 xj_l[NB * 16 * 32];
  __shared__ __align__(16) __bf16 ea_l[NB * 16 * 32];
  __shared__ float sm[NB * NHEADS * 17];               // +1 pad: 160-float stride aliases banks

  // ---- zero the pad rows 10..15 of every tile (384 B per tile per array = 24 x 16B) ----
  {
    const f32x4 z = {0.f, 0.f, 0.f, 0.f};
    for (int idx = tid; idx < NB * 24 * 3; idx += 320) {
      const int arr = idx / (NB * 24);
      const int k   = idx - arr * (NB * 24);
      const int t   = k / 24, o = k - t * 24;
      char* base = arr == 0 ? (char*)xi_l : (arr == 1 ? (char*)xj_l : (char*)ea_l);
      *(f32x4*)(base + t * 1024 + 640 + o * 16) = z;
    }
  }

  // ---- stage 80 edges: task = (edge-local 0..79, quad 0..7), 2 tasks/thread ----
  const int e0 = blockIdx.x * (NB * 10);
  for (int tau = tid; tau < 640; tau += 320) {
    const int el = tau >> 3, quad = tau & 7;
    const int g = el / 10;
    const int r = el - g * 10;
    const int e = e0 + el;
    const int ri = eidx[e];
    const int ci = eidx[NEDGES + e];
    const float4 xi4 = *(const float4*)(x + ri * HDIM + quad * 4);
    const float4 xj4 = *(const float4*)(x + ci * HDIM + quad * 4);
    const float4 ea4 = *(const float4*)(ea + e * HDIM + quad * 4);
    const int o1 = ((r * 64 + quad * 8) ^ ((r & 3) << 4)) + g * 1024;
    *(bf16x4*)((char*)xi_l + o1) = cvt4(xi4);
    *(bf16x4*)((char*)xj_l + o1) = cvt4(xj4);
    *(bf16x4*)((char*)ea_l + o1) = cvt4(ea4);
  }

  // ---- per-lane constants: W fragments (K=32 halves), att, GroupNorm affine ----
  bf16x8 wf1[4], wf2[4];
#pragma unroll
  for (int t = 0; t < 4; ++t) {
    const int c = 64 * w + 16 * t + lr;
#pragma unroll
    for (int j = 0; j < 8; ++j) {
      const int k = lq * 8 + j;
      wf1[t][j] = (__bf16)W[k * NCOLS + c];
      wf2[t][j] = (__bf16)W[(32 + k) * NCOLS + c];
    }
  }
  float atti[4], attj[4];
#pragma unroll
  for (int t = 0; t < 4; ++t) {
    const int h  = 2 * w + (t >> 1);
    const int cc = 16 * (t & 1) + lr;
    atti[t] = att[h * 64 + cc];
    attj[t] = att[h * 64 + 32 + cc];
  }
  float gs[2], gb[2];
#pragma unroll
  for (int hh = 0; hh < 2; ++hh) {
    const int h = 2 * w + hh;
    const float inv = rsqrtf(rvar[h] + EPSV);
    gs[hh] = inv * gamma[h];
    gb[hh] = beta[h] - rmean[h] * inv * gamma[h];
  }

  __syncthreads();

  const int roff = (lr * 64 + lq * 16) ^ ((lr & 3) << 4);
  const f32x4 zero4 = {0.f, 0.f, 0.f, 0.f};

  // ---- pass 1: logits for all tiles ----
#pragma unroll
  for (int nt = 0; nt < NB; ++nt) {
    const bf16x8 aif = *(const bf16x8*)((const char*)xi_l + nt * 1024 + roff);
    const bf16x8 ajf = *(const bf16x8*)((const char*)xj_l + nt * 1024 + roff);
    const bf16x8 ef  = *(const bf16x8*)((const char*)ea_l + nt * 1024 + roff);
    float plog[2][4];
#pragma unroll
    for (int hh = 0; hh < 2; ++hh)
#pragma unroll
      for (int p = 0; p < 4; ++p) plog[hh][p] = 0.f;
#pragma unroll
    for (int t = 0; t < 4; ++t) {
      f32x4 c  = __builtin_amdgcn_mfma_f32_16x16x32_bf16(ef,  wf2[t], zero4, 0, 0, 0);
      f32x4 ai = __builtin_amdgcn_mfma_f32_16x16x32_bf16(aif, wf1[t], c,     0, 0, 0);
      f32x4 aj = __builtin_amdgcn_mfma_f32_16x16x32_bf16(ajf, wf1[t], c,     0, 0, 0);
      const int hh = t >> 1;
#pragma unroll
      for (int p = 0; p < 4; ++p)
        plog[hh][p] += leaky_f(ai[p]) * atti[t] + leaky_f(aj[p]) * attj[t];
    }
#pragma unroll
    for (int m = 1; m <= 8; m <<= 1)
#pragma unroll
      for (int hh = 0; hh < 2; ++hh)
#pragma unroll
        for (int p = 0; p < 4; ++p)
          plog[hh][p] += __shfl_xor(plog[hh][p], m, 64);
    if (lr == 0) {
#pragma unroll
      for (int hh = 0; hh < 2; ++hh)
#pragma unroll
        for (int p = 0; p < 4; ++p)
          sm[nt * (NHEADS * 17) + (2 * w + hh) * 17 + lq * 4 + p] =
              leaky_f(plog[hh][p]) * gs[hh] + gb[hh];
    }
  }
  __syncthreads();

  // ---- softmax over heads: one thread per (tile,row), pads included (finite junk, unused) ----
  if (tid < NB * 16) {
    const int g = tid >> 4, rr = tid & 15;
    float v[NHEADS];
    float mx = -1e30f;
#pragma unroll
    for (int h = 0; h < NHEADS; ++h) {
      v[h] = sm[g * (NHEADS * 17) + h * 17 + rr];
      mx = fmaxf(mx, v[h]);
    }
    float s = 0.f;
#pragma unroll
    for (int h = 0; h < NHEADS; ++h) { v[h] = __expf(v[h] - mx); s += v[h]; }
    const float inv = 1.f / s;
#pragma unroll
    for (int h = 0; h < NHEADS; ++h)
      sm[g * (NHEADS * 17) + h * 17 + rr] = v[h] * inv;
  }
  __syncthreads();

  // ---- pass 2: recompute j-side, weight, group-sum, scatter ----
#pragma unroll
  for (int nt = 0; nt < NB; ++nt) {
    const bf16x8 ajf = *(const bf16x8*)((const char*)xj_l + nt * 1024 + roff);
    const bf16x8 ef  = *(const bf16x8*)((const char*)ea_l + nt * 1024 + roff);
    const int q = blockIdx.x * NB + nt;
#pragma unroll
    for (int t = 0; t < 4; ++t) {
      f32x4 c  = __builtin_amdgcn_mfma_f32_16x16x32_bf16(ef,  wf2[t], zero4, 0, 0, 0);
      f32x4 aj = __builtin_amdgcn_mfma_f32_16x16x32_bf16(ajf, wf1[t], c,     0, 0, 0);
      const int h = 2 * w + (t >> 1);
      float s_t = 0.f;
#pragma unroll
      for (int p = 0; p < 4; ++p)
        s_t += leaky_f(aj[p]) * sm[nt * (NHEADS * 17) + h * 17 + lq * 4 + p]; // pads: aj==0
      s_t += __shfl_xor(s_t, 16, 64);
      s_t += __shfl_xor(s_t, 32, 64);
      if (lq == 0) {
        const int a = h * NQ + q;          // slot consuming (group q, head h)
        const int n = eidx[a];             // destination node = row[a]
        atomicAdd(&out[n * HDIM + 16 * (t & 1) + lr], 0.1f * s_t);
      }
    }
  }
}

extern "C" void kernel_launch(void* const* d_in, const int* in_sizes, int n_in,
                              void* d_out, int out_size, void* d_ws, size_t ws_size,
                              hipStream_t stream) {
  const float* x     = (const float*)d_in[0];
  const int*   eidx  = (const int*)  d_in[1];
  const float* ea    = (const float*)d_in[2];
  const float* W     = (const float*)d_in[3];
  const float* att   = (const float*)d_in[4];
  const float* bias  = (const float*)d_in[5];
  const float* gamma = (const float*)d_in[6];
  const float* beta  = (const float*)d_in[7];
  const float* rmean = (const float*)d_in[8];
  const float* rvar  = (const float*)d_in[9];
  float* out = (float*)d_out;

  agat_init_out<<<(NNODES * HDIM + 255) / 256, 256, 0, stream>>>(out, bias);
  agat_fused<<<GRID_MAIN, 320, 0, stream>>>(x, eidx, ea, W, att, gamma, beta,
                                            rmean, rvar, out);
}

// Round 3
// 289.115 us; speedup vs baseline: 1.4088x; 1.1358x over previous
//
#include <hip/hip_runtime.h>

#define NNODES 25000
#define NEDGES 400000
#define HDIM   32
#define NHEADS 10
#define NCOLS  320          // HEADS*HDIM
#define NEG    0.2f
#define EPSV   1e-5f
#define NQ     40000        // NEDGES/10 edge-groups
#define NB     8            // edge-groups (tiles) per batch
#define NBATCH (NQ / NB)    // 5000 tile-batches
#define GRID_MAIN 1280      // persistent blocks: 5/CU (LDS-limited)
#define NITER 4             // ceil(NBATCH / GRID_MAIN)

typedef __bf16 bf16x4 __attribute__((ext_vector_type(4)));
typedef __bf16 bf16x8 __attribute__((ext_vector_type(8)));
typedef float  f32x4  __attribute__((ext_vector_type(4)));

__device__ __forceinline__ float leaky_f(float v) { return v >= 0.0f ? v : NEG * v; }

__device__ __forceinline__ bf16x4 cvt4(float4 v) {
  bf16x4 r; r[0] = (__bf16)v.x; r[1] = (__bf16)v.y; r[2] = (__bf16)v.z; r[3] = (__bf16)v.w;
  return r;
}

__global__ void agat_init_out(float* __restrict__ out, const float* __restrict__ bias) {
  int i = blockIdx.x * 256 + threadIdx.x;
  if (i < NNODES * HDIM) out[i] = bias[i & (HDIM - 1)];
}

// Persistent blocks: 1280 blocks x 320 threads (5 waves), each loops over up to 4
// tile-batches of NB=8 16-row M-tiles (10 real edges + 6 zero pad rows per tile).
// Wave w owns heads {2w,2w+1} = cols [64w,64w+64). Constants (W frags, att, GN)
// load once per block. Edge indices for stage(it+1) prefetch one iteration ahead.
__global__ __launch_bounds__(320) void agat_fused(
    const float* __restrict__ x,
    const int*   __restrict__ eidx,
    const float* __restrict__ ea,
    const float* __restrict__ W,
    const float* __restrict__ att,
    const float* __restrict__ gamma,
    const float* __restrict__ beta,
    const float* __restrict__ rmean,
    const float* __restrict__ rvar,
    float*       __restrict__ out)
{
  const int tid = threadIdx.x;
  const int w  = tid >> 6;   // wave 0..4
  const int l  = tid & 63;
  const int lq = l >> 4;     // lane quarter = 4-row group
  const int lr = l & 15;     // column-within-16

  __shared__ __align__(16) __bf16 xi_l[NB * 16 * 32];  // 8 KB, rows XOR-swizzled in 64B
  __shared__ __align__(16) __bf16 xj_l[NB * 16 * 32];
  __shared__ __align__(16) __bf16 ea_l[NB * 16 * 32];
  __shared__ float sm[NB * NHEADS * 17];               // stride 17 breaks bank aliasing

  // ---- zero pad rows 10..15 of every tile (disjoint from swizzled rows 0..9) ----
  {
    const f32x4 z = {0.f, 0.f, 0.f, 0.f};
    for (int idx = tid; idx < NB * 24 * 3; idx += 320) {
      const int arr = idx / (NB * 24);
      const int k   = idx - arr * (NB * 24);
      const int t   = k / 24, o = k - t * 24;
      char* base = arr == 0 ? (char*)xi_l : (arr == 1 ? (char*)xj_l : (char*)ea_l);
      *(f32x4*)(base + t * 1024 + 640 + o * 16) = z;
    }
  }

  // ---- prefetch edge indices for iteration 0 (tasks tid, tid+320) ----
  int ri0, ci0, ri1, ci1;
  {
    const int e0 = blockIdx.x * (NB * 10);
    ri0 = eidx[e0 + (tid >> 3)];
    ci0 = eidx[NEDGES + e0 + (tid >> 3)];
    ri1 = eidx[e0 + ((tid + 320) >> 3)];
    ci1 = eidx[NEDGES + e0 + ((tid + 320) >> 3)];
  }

  // ---- stage iteration 0 ----
  {
    const int e0 = blockIdx.x * (NB * 10);
#pragma unroll
    for (int s = 0; s < 2; ++s) {
      const int tau = tid + s * 320;
      const int el = tau >> 3, quad = tau & 7;
      const int g = el / 10;
      const int r = el - g * 10;
      const int ri = s == 0 ? ri0 : ri1;
      const int ci = s == 0 ? ci0 : ci1;
      const float4 xi4 = *(const float4*)(x + ri * HDIM + quad * 4);
      const float4 xj4 = *(const float4*)(x + ci * HDIM + quad * 4);
      const float4 ea4 = *(const float4*)(ea + (e0 + el) * HDIM + quad * 4);
      const int o1 = ((r * 64 + quad * 8) ^ ((r & 3) << 4)) + g * 1024;
      *(bf16x4*)((char*)xi_l + o1) = cvt4(xi4);
      *(bf16x4*)((char*)xj_l + o1) = cvt4(xj4);
      *(bf16x4*)((char*)ea_l + o1) = cvt4(ea4);
    }
  }

  // ---- per-lane constants (once per persistent block) ----
  bf16x8 wf1[4], wf2[4];
#pragma unroll
  for (int t = 0; t < 4; ++t) {
    const int c = 64 * w + 16 * t + lr;
#pragma unroll
    for (int j = 0; j < 8; ++j) {
      const int k = lq * 8 + j;
      wf1[t][j] = (__bf16)W[k * NCOLS + c];
      wf2[t][j] = (__bf16)W[(32 + k) * NCOLS + c];
    }
  }
  float atti[4], attj[4];
#pragma unroll
  for (int t = 0; t < 4; ++t) {
    const int h  = 2 * w + (t >> 1);
    const int cc = 16 * (t & 1) + lr;
    atti[t] = att[h * 64 + cc];
    attj[t] = att[h * 64 + 32 + cc];
  }
  float gs[2], gb[2];
#pragma unroll
  for (int hh = 0; hh < 2; ++hh) {
    const int h = 2 * w + hh;
    const float inv = rsqrtf(rvar[h] + EPSV);
    gs[hh] = inv * gamma[h];
    gb[hh] = beta[h] - rmean[h] * inv * gamma[h];
  }

  const int roff = (lr * 64 + lq * 16) ^ ((lr & 3) << 4);
  const f32x4 zero4 = {0.f, 0.f, 0.f, 0.f};

  for (int it = 0; it < NITER; ++it) {
    const int batch = blockIdx.x + it * GRID_MAIN;
    if (batch >= NBATCH) break;                      // block-uniform

    // prefetch edge indices for stage(it+1); regs already consumed by stage(it)
    const int nb = batch + GRID_MAIN;
    if (nb < NBATCH) {
      const int e0n = nb * (NB * 10);
      ri0 = eidx[e0n + (tid >> 3)];
      ci0 = eidx[NEDGES + e0n + (tid >> 3)];
      ri1 = eidx[e0n + ((tid + 320) >> 3)];
      ci1 = eidx[NEDGES + e0n + ((tid + 320) >> 3)];
    }

    __syncthreads();                                 // [A] stage(it) visible

    // ---- pass 1: logits ----
#pragma unroll
    for (int nt = 0; nt < NB; ++nt) {
      const bf16x8 aif = *(const bf16x8*)((const char*)xi_l + nt * 1024 + roff);
      const bf16x8 ajf = *(const bf16x8*)((const char*)xj_l + nt * 1024 + roff);
      const bf16x8 ef  = *(const bf16x8*)((const char*)ea_l + nt * 1024 + roff);
      float plog[2][4];
#pragma unroll
      for (int hh = 0; hh < 2; ++hh)
#pragma unroll
        for (int p = 0; p < 4; ++p) plog[hh][p] = 0.f;
#pragma unroll
      for (int t = 0; t < 4; ++t) {
        f32x4 c  = __builtin_amdgcn_mfma_f32_16x16x32_bf16(ef,  wf2[t], zero4, 0, 0, 0);
        f32x4 ai = __builtin_amdgcn_mfma_f32_16x16x32_bf16(aif, wf1[t], c,     0, 0, 0);
        f32x4 aj = __builtin_amdgcn_mfma_f32_16x16x32_bf16(ajf, wf1[t], c,     0, 0, 0);
        const int hh = t >> 1;
#pragma unroll
        for (int p = 0; p < 4; ++p)
          plog[hh][p] += leaky_f(ai[p]) * atti[t] + leaky_f(aj[p]) * attj[t];
      }
#pragma unroll
      for (int m = 1; m <= 8; m <<= 1)
#pragma unroll
        for (int hh = 0; hh < 2; ++hh)
#pragma unroll
          for (int p = 0; p < 4; ++p)
            plog[hh][p] += __shfl_xor(plog[hh][p], m, 64);
      if (lr == 0) {
#pragma unroll
        for (int hh = 0; hh < 2; ++hh)
#pragma unroll
          for (int p = 0; p < 4; ++p)
            sm[nt * (NHEADS * 17) + (2 * w + hh) * 17 + lq * 4 + p] =
                leaky_f(plog[hh][p]) * gs[hh] + gb[hh];
      }
    }
    __syncthreads();                                 // [B] sm logits visible

    // ---- softmax over heads: one thread per (tile,row) ----
    if (tid < NB * 16) {
      const int g = tid >> 4, rr = tid & 15;
      float v[NHEADS];
      float mx = -1e30f;
#pragma unroll
      for (int h = 0; h < NHEADS; ++h) {
        v[h] = sm[g * (NHEADS * 17) + h * 17 + rr];
        mx = fmaxf(mx, v[h]);
      }
      float s = 0.f;
#pragma unroll
      for (int h = 0; h < NHEADS; ++h) { v[h] = __expf(v[h] - mx); s += v[h]; }
      const float inv = 1.f / s;
#pragma unroll
      for (int h = 0; h < NHEADS; ++h)
        sm[g * (NHEADS * 17) + h * 17 + rr] = v[h] * inv;
    }
    __syncthreads();                                 // [C] weights visible

    // ---- pass 2: recompute j-side, weight, 16-row group-sum, merged scatter ----
#pragma unroll
    for (int nt = 0; nt < NB; ++nt) {
      const bf16x8 ajf = *(const bf16x8*)((const char*)xj_l + nt * 1024 + roff);
      const bf16x8 ef  = *(const bf16x8*)((const char*)ea_l + nt * 1024 + roff);
      const int q = batch * NB + nt;
      float st[4];
#pragma unroll
      for (int t = 0; t < 4; ++t) {
        f32x4 c  = __builtin_amdgcn_mfma_f32_16x16x32_bf16(ef,  wf2[t], zero4, 0, 0, 0);
        f32x4 aj = __builtin_amdgcn_mfma_f32_16x16x32_bf16(ajf, wf1[t], c,     0, 0, 0);
        const int h = 2 * w + (t >> 1);
        float s_t = 0.f;
#pragma unroll
        for (int p = 0; p < 4; ++p)
          s_t += leaky_f(aj[p]) * sm[nt * (NHEADS * 17) + h * 17 + lq * 4 + p];
        s_t += __shfl_xor(s_t, 16, 64);
        s_t += __shfl_xor(s_t, 32, 64);              // all lanes now hold 16-row sum
        st[t] = s_t;
      }
      // merged 64-lane atomic: lane takes t = lq -> head 2w+(lq>>1), col 16*(lq&1)+lr
      const float v01 = (lq & 1) ? st[1] : st[0];
      const float v23 = (lq & 1) ? st[3] : st[2];
      const float v   = (lq & 2) ? v23 : v01;
      const int h = 2 * w + (lq >> 1);
      const int a = h * NQ + q;                      // slot consuming (group q, head h)
      const int n = eidx[a];                         // destination node
      atomicAdd(&out[n * HDIM + 16 * (lq & 1) + lr], 0.1f * v);
    }
    __syncthreads();                                 // [D] LDS free for next stage

    // ---- stage(it+1) with prefetched indices ----
    if (nb < NBATCH) {
      const int e0n = nb * (NB * 10);
#pragma unroll
      for (int s = 0; s < 2; ++s) {
        const int tau = tid + s * 320;
        const int el = tau >> 3, quad = tau & 7;
        const int g = el / 10;
        const int r = el - g * 10;
        const int ri = s == 0 ? ri0 : ri1;
        const int ci = s == 0 ? ci0 : ci1;
        const float4 xi4 = *(const float4*)(x + ri * HDIM + quad * 4);
        const float4 xj4 = *(const float4*)(x + ci * HDIM + quad * 4);
        const float4 ea4 = *(const float4*)(ea + (e0n + el) * HDIM + quad * 4);
        const int o1 = ((r * 64 + quad * 8) ^ ((r & 3) << 4)) + g * 1024;
        *(bf16x4*)((char*)xi_l + o1) = cvt4(xi4);
        *(bf16x4*)((char*)xj_l + o1) = cvt4(xj4);
        *(bf16x4*)((char*)ea_l + o1) = cvt4(ea4);
      }
    }
  }
}

extern "C" void kernel_launch(void* const* d_in, const int* in_sizes, int n_in,
                              void* d_out, int out_size, void* d_ws, size_t ws_size,
                              hipStream_t stream) {
  const float* x     = (const float*)d_in[0];
  const int*   eidx  = (const int*)  d_in[1];
  const float* ea    = (const float*)d_in[2];
  const float* W     = (const float*)d_in[3];
  const float* att   = (const float*)d_in[4];
  const float* bias  = (const float*)d_in[5];
  const float* gamma = (const float*)d_in[6];
  const float* beta  = (const float*)d_in[7];
  const float* rmean = (const float*)d_in[8];
  const float* rvar  = (const float*)d_in[9];
  float* out = (float*)d_out;

  agat_init_out<<<(NNODES * HDIM + 255) / 256, 256, 0, stream>>>(out, bias);
  agat_fused<<<GRID_MAIN, 320, 0, stream>>>(x, eidx, ea, W, att, gamma, beta,
                                            rmean, rvar, out);
}